// Round 1
// baseline (164.679 us; speedup 1.0000x reference)
//
#include <hip/hip_runtime.h>
#include <math.h>

// Problem: weighted-L1 loss (WL1) over [B=16, C=3, H=512, W=512] fp32.
//   r   = sum_c |hr - sr| / 255           (residual_sr,  [B,1,H,W])
//   e   = sum_c |hr - sr_ema| / 255       (residual_ema)
//   patch_w = (unbiased var of r over each sample)^0.2       [B]
//   pixel_w = unbiased 3x3 local var of r (reflect pad)      [B,H,W]
//   w = patch_w * pixel_w, zeroed where r < e
//   loss = mean over [B,3,H,W] of |w*sr - w*hr|  ~= (1/N) sum w*255*r
//
// Single main pass: each block owns a 64(w) x 4(h) tile, recomputes r for
// tile+halo (6x66) into LDS, computes local var + masked contribution, and
// emits per-block partials (sum r, sum r^2, sum contrib). patch_w is applied
// per-batch in a tiny second kernel; third kernel folds 16 values to scalar.

#define BB 16
#define HH 512
#define WW 512
#define HW (HH * WW)
#define CHW (3 * HW)
#define BLOCKS_PER_BATCH 1024   // (512/4) * (512/64)
#define NBLOCKS (BB * BLOCKS_PER_BATCH)

__global__ __launch_bounds__(256) void wl1_main(
    const float* __restrict__ sr, const float* __restrict__ srema,
    const float* __restrict__ hr,
    float* __restrict__ p_sum, float* __restrict__ p_sum2,
    float* __restrict__ p_loss) {
  __shared__ float rt[6][66];  // 6 rows x 66 cols halo tile of r
  const int bid = blockIdx.x;
  const int b = bid >> 10;
  const int t = bid & 1023;
  const int h0 = (t >> 3) << 2;  // tile_h * 4
  const int w0 = (t & 7) << 6;   // tile_w * 64
  const int tid = threadIdx.x;
  const float* __restrict__ srb = sr + (size_t)b * CHW;
  const float* __restrict__ hrb = hr + (size_t)b * CHW;

  // Stage A: cooperative fill of r tile (with reflect-padded halo)
  for (int idx = tid; idx < 6 * 66; idx += 256) {
    int row = idx / 66;
    int col = idx - row * 66;
    int gh = h0 - 1 + row;
    gh = gh < 0 ? -gh : gh;
    gh = gh >= HH ? 2 * HH - 2 - gh : gh;
    int gw = w0 - 1 + col;
    gw = gw < 0 ? -gw : gw;
    gw = gw >= WW ? 2 * WW - 2 - gw : gw;
    int base = gh * WW + gw;
    float s = fabsf(hrb[base] - srb[base]) +
              fabsf(hrb[base + HW] - srb[base + HW]) +
              fabsf(hrb[base + 2 * HW] - srb[base + 2 * HW]);
    rt[row][col] = s / 255.0f;
  }
  __syncthreads();

  const int lw = tid & 63, lh = tid >> 6;
  // Stage B: 3x3 unbiased local variance around center (lh+1, lw+1)
  float s = 0.f, sq = 0.f;
#pragma unroll
  for (int dr = 0; dr < 3; ++dr)
#pragma unroll
    for (int dc = 0; dc < 3; ++dc) {
      float v = rt[lh + dr][lw + dc];
      s += v;
      sq += v * v;
    }
  float pvar = (sq - s * s / 9.0f) / 8.0f;
  float rc = rt[lh + 1][lw + 1];

  // residual_ema at the center pixel
  const int h = h0 + lh, w = w0 + lw;
  const int base = h * WW + w;
  const float* __restrict__ eb = srema + (size_t)b * CHW;
  float e = (fabsf(hrb[base] - eb[base]) +
             fabsf(hrb[base + HW] - eb[base + HW]) +
             fabsf(hrb[base + 2 * HW] - eb[base + 2 * HW])) /
            255.0f;

  // masked contribution (patch_w deferred): pixel_var * sum_c|sr-hr|
  float contrib = (rc < e) ? 0.0f : pvar * (255.0f * rc);

  // block reduce (rc, rc^2, contrib)
  float v1 = rc, v2 = rc * rc, v3 = contrib;
#pragma unroll
  for (int off = 32; off > 0; off >>= 1) {
    v1 += __shfl_down(v1, off, 64);
    v2 += __shfl_down(v2, off, 64);
    v3 += __shfl_down(v3, off, 64);
  }
  __shared__ float red[3][4];
  const int wave = tid >> 6, lane = tid & 63;
  if (lane == 0) {
    red[0][wave] = v1;
    red[1][wave] = v2;
    red[2][wave] = v3;
  }
  __syncthreads();
  if (tid == 0) {
    p_sum[bid] = red[0][0] + red[0][1] + red[0][2] + red[0][3];
    p_sum2[bid] = red[1][0] + red[1][1] + red[1][2] + red[1][3];
    p_loss[bid] = red[2][0] + red[2][1] + red[2][2] + red[2][3];
  }
}

// One block per batch: fold 1024 partials, compute patch_w, emit pw * S_b.
__global__ __launch_bounds__(256) void wl1_batch(
    const float* __restrict__ p_sum, const float* __restrict__ p_sum2,
    const float* __restrict__ p_loss, double* __restrict__ lossb) {
  const int b = blockIdx.x, tid = threadIdx.x;
  double s = 0.0, s2 = 0.0, sl = 0.0;
  for (int k = tid; k < BLOCKS_PER_BATCH; k += 256) {
    int i = b * BLOCKS_PER_BATCH + k;
    s += (double)p_sum[i];
    s2 += (double)p_sum2[i];
    sl += (double)p_loss[i];
  }
#pragma unroll
  for (int off = 32; off > 0; off >>= 1) {
    s += __shfl_down(s, off, 64);
    s2 += __shfl_down(s2, off, 64);
    sl += __shfl_down(sl, off, 64);
  }
  __shared__ double red[3][4];
  const int wave = tid >> 6, lane = tid & 63;
  if (lane == 0) {
    red[0][wave] = s;
    red[1][wave] = s2;
    red[2][wave] = sl;
  }
  __syncthreads();
  if (tid == 0) {
    double S = red[0][0] + red[0][1] + red[0][2] + red[0][3];
    double S2 = red[1][0] + red[1][1] + red[1][2] + red[1][3];
    double SL = red[2][0] + red[2][1] + red[2][2] + red[2][3];
    const double n = (double)HW;  // 262144 pixels per sample
    double var = (S2 - S * S / n) / (n - 1.0);
    double pw = pow(var, 0.2);
    lossb[b] = pw * SL;
  }
}

__global__ void wl1_final(const double* __restrict__ lossb,
                          float* __restrict__ out) {
  const int tid = threadIdx.x;
  double v = (tid < BB) ? lossb[tid] : 0.0;
#pragma unroll
  for (int off = 32; off > 0; off >>= 1) v += __shfl_down(v, off, 64);
  if (tid == 0) out[0] = (float)(v / (double)(BB * 3 * HW));
}

extern "C" void kernel_launch(void* const* d_in, const int* in_sizes, int n_in,
                              void* d_out, int out_size, void* d_ws,
                              size_t ws_size, hipStream_t stream) {
  const float* sr = (const float*)d_in[0];
  const float* srema = (const float*)d_in[1];
  const float* hr = (const float*)d_in[2];
  float* out = (float*)d_out;

  float* p_sum = (float*)d_ws;
  float* p_sum2 = p_sum + NBLOCKS;
  float* p_loss = p_sum2 + NBLOCKS;
  double* lossb = (double*)((char*)d_ws + (size_t)3 * NBLOCKS * sizeof(float));

  wl1_main<<<NBLOCKS, 256, 0, stream>>>(sr, srema, hr, p_sum, p_sum2, p_loss);
  wl1_batch<<<BB, 256, 0, stream>>>(p_sum, p_sum2, p_loss, lossb);
  wl1_final<<<1, 64, 0, stream>>>(lossb, out);
}

// Round 2
// 159.021 us; speedup vs baseline: 1.0356x; 1.0356x over previous
//
#include <hip/hip_runtime.h>
#include <math.h>

// WL1 loss over [B=16, C=3, H=512, W=512] fp32.
//   r = sum_c|hr-sr|/255 ; e = sum_c|hr-ema|/255
//   patch_w[b] = (unbiased var of r over sample)^0.2
//   pixel_w = unbiased 3x3 local var of r (reflect pad)
//   loss = mean(|w*sr - w*hr|) = (1/N) sum patch_w * pixel_w * mask * 255*r
//
// R1: float4-vectorized main pass. Block = 256x16 tile (1024 blocks = 4/CU).
// Halo r-tile (18 rows x 258 cols) in LDS, centers stored at col+4 so all
// LDS accesses are 16B-aligned b128. Stage B: 4x4 outputs/thread with
// column-sum reuse. Reductions fused into one 1024-thread kernel.

#define BB 16
#define HH 512
#define WW 512
#define HW (HH * WW)
#define CHW (3 * HW)
#define TILES_PER_BATCH 64  // 32 (h) x 2 (w)
#define NBLOCKS (BB * TILES_PER_BATCH)
#define LDS_STRIDE 264      // cols: 3 = left halo, 4..259 = centers, 260 = right halo

__device__ __forceinline__ int reflect_h(int gh) {
  gh = gh < 0 ? -gh : gh;
  return gh >= HH ? 2 * HH - 2 - gh : gh;
}

__global__ __launch_bounds__(256) void wl1_main(
    const float* __restrict__ sr, const float* __restrict__ srema,
    const float* __restrict__ hr,
    float* __restrict__ p_sum, float* __restrict__ p_sum2,
    float* __restrict__ p_loss) {
  __shared__ float rt[18][LDS_STRIDE];
  const int bid = blockIdx.x;
  const int b = bid >> 6;
  const int t = bid & 63;
  const int h0 = (t >> 1) << 4;  // 0,16,...,496
  const int w0 = (t & 1) << 8;   // 0 or 256
  const int tid = threadIdx.x;
  const int c4 = tid & 63;       // float4 column group (0..63)
  const int rs = tid >> 6;       // row-sub (0..3)
  const float* __restrict__ srb = sr + (size_t)b * CHW;
  const float* __restrict__ hrb = hr + (size_t)b * CHW;
  const float* __restrict__ eb = srema + (size_t)b * CHW;

  // Stage A: interior halo rows, float4 per lane (18 rows, 4 rows/iter)
#pragma unroll
  for (int it = 0; it < 5; ++it) {
    int row = it * 4 + rs;
    if (row < 18) {
      int gh = reflect_h(h0 - 1 + row);
      const float* hb = hrb + gh * WW + w0 + 4 * c4;
      const float* sb = srb + gh * WW + w0 + 4 * c4;
      float4 ha = *(const float4*)(hb);
      float4 hbv = *(const float4*)(hb + HW);
      float4 hc = *(const float4*)(hb + 2 * HW);
      float4 sa = *(const float4*)(sb);
      float4 sbv = *(const float4*)(sb + HW);
      float4 sc = *(const float4*)(sb + 2 * HW);
      float4 r4;
      r4.x = (fabsf(ha.x - sa.x) + fabsf(hbv.x - sbv.x) + fabsf(hc.x - sc.x)) / 255.0f;
      r4.y = (fabsf(ha.y - sa.y) + fabsf(hbv.y - sbv.y) + fabsf(hc.y - sc.y)) / 255.0f;
      r4.z = (fabsf(ha.z - sa.z) + fabsf(hbv.z - sbv.z) + fabsf(hc.z - sc.z)) / 255.0f;
      r4.w = (fabsf(ha.w - sa.w) + fabsf(hbv.w - sbv.w) + fabsf(hc.w - sc.w)) / 255.0f;
      *(float4*)&rt[row][4 + 4 * c4] = r4;
    }
  }
  // Stage A2: left/right halo columns (36 scalar items)
  if (tid < 36) {
    int row = tid >> 1, side = tid & 1;
    int gh = reflect_h(h0 - 1 + row);
    int gw = side ? w0 + 256 : w0 - 1;
    if (gw < 0) gw = 1;
    if (gw > 511) gw = 1022 - gw;
    int base = gh * WW + gw;
    float v = (fabsf(hrb[base] - srb[base]) +
               fabsf(hrb[base + HW] - srb[base + HW]) +
               fabsf(hrb[base + 2 * HW] - srb[base + 2 * HW])) /
              255.0f;
    rt[row][side ? 260 : 3] = v;
  }
  __syncthreads();

  // Stage B: each thread -> 4 rows x 4 cols of outputs
  float v1 = 0.f, v2 = 0.f, v3 = 0.f;
  const int row0 = rs * 4;  // output row base within tile
#pragma unroll
  for (int rr = 0; rr < 4; ++rr) {
    const int orow = row0 + rr;  // 0..15, LDS center row = orow+1
    float cs[6] = {0, 0, 0, 0, 0, 0}, cq[6] = {0, 0, 0, 0, 0, 0};
    float center[4];
#pragma unroll
    for (int dr = 0; dr < 3; ++dr) {
      const float* lp = &rt[orow + dr][4 * c4];
      float4 a = *(const float4*)(lp);
      float4 bq = *(const float4*)(lp + 4);
      float4 cq4 = *(const float4*)(lp + 8);
      float f3 = a.w, f4 = bq.x, f5 = bq.y, f6 = bq.z, f7 = bq.w, f8 = cq4.x;
      cs[0] += f3; cq[0] += f3 * f3;
      cs[1] += f4; cq[1] += f4 * f4;
      cs[2] += f5; cq[2] += f5 * f5;
      cs[3] += f6; cq[3] += f6 * f6;
      cs[4] += f7; cq[4] += f7 * f7;
      cs[5] += f8; cq[5] += f8 * f8;
      if (dr == 1) { center[0] = f4; center[1] = f5; center[2] = f6; center[3] = f7; }
    }
    // residual_ema for this row strip (float4 loads)
    const int gbase = (h0 + orow) * WW + w0 + 4 * c4;
    float4 ha = *(const float4*)(hrb + gbase);
    float4 hb2 = *(const float4*)(hrb + gbase + HW);
    float4 hc = *(const float4*)(hrb + gbase + 2 * HW);
    float4 ea = *(const float4*)(eb + gbase);
    float4 eb2 = *(const float4*)(eb + gbase + HW);
    float4 ec = *(const float4*)(eb + gbase + 2 * HW);
    float e4[4];
    e4[0] = (fabsf(ha.x - ea.x) + fabsf(hb2.x - eb2.x) + fabsf(hc.x - ec.x)) / 255.0f;
    e4[1] = (fabsf(ha.y - ea.y) + fabsf(hb2.y - eb2.y) + fabsf(hc.y - ec.y)) / 255.0f;
    e4[2] = (fabsf(ha.z - ea.z) + fabsf(hb2.z - eb2.z) + fabsf(hc.z - ec.z)) / 255.0f;
    e4[3] = (fabsf(ha.w - ea.w) + fabsf(hb2.w - eb2.w) + fabsf(hc.w - ec.w)) / 255.0f;
#pragma unroll
    for (int cc = 0; cc < 4; ++cc) {
      float s = cs[cc] + cs[cc + 1] + cs[cc + 2];
      float q = cq[cc] + cq[cc + 1] + cq[cc + 2];
      float pvar = (q - s * s / 9.0f) / 8.0f;
      float rc = center[cc];
      v1 += rc;
      v2 += rc * rc;
      if (rc >= e4[cc]) v3 += pvar * (255.0f * rc);
    }
  }

  // block reduce
#pragma unroll
  for (int off = 32; off > 0; off >>= 1) {
    v1 += __shfl_down(v1, off, 64);
    v2 += __shfl_down(v2, off, 64);
    v3 += __shfl_down(v3, off, 64);
  }
  __shared__ float red[3][4];
  if (c4 == 0) {
    red[0][rs] = v1;
    red[1][rs] = v2;
    red[2][rs] = v3;
  }
  __syncthreads();
  if (tid == 0) {
    p_sum[bid] = red[0][0] + red[0][1] + red[0][2] + red[0][3];
    p_sum2[bid] = red[1][0] + red[1][1] + red[1][2] + red[1][3];
    p_loss[bid] = red[2][0] + red[2][1] + red[2][2] + red[2][3];
  }
}

// Single fused reduction: wave w handles batch w (64 partials each).
__global__ __launch_bounds__(1024) void wl1_reduce(
    const float* __restrict__ p_sum, const float* __restrict__ p_sum2,
    const float* __restrict__ p_loss, float* __restrict__ out) {
  const int tid = threadIdx.x;
  const int b = tid >> 6, k = tid & 63;
  const int i = b * TILES_PER_BATCH + k;
  double s = (double)p_sum[i], s2 = (double)p_sum2[i], sl = (double)p_loss[i];
#pragma unroll
  for (int off = 32; off > 0; off >>= 1) {
    s += __shfl_down(s, off, 64);
    s2 += __shfl_down(s2, off, 64);
    sl += __shfl_down(sl, off, 64);
  }
  __shared__ double acc[BB];
  if (k == 0) {
    const double n = (double)HW;
    double var = (s2 - s * s / n) / (n - 1.0);
    acc[b] = pow(var, 0.2) * sl;
  }
  __syncthreads();
  if (tid == 0) {
    double tot = 0.0;
#pragma unroll
    for (int j = 0; j < BB; ++j) tot += acc[j];
    out[0] = (float)(tot / (double)((size_t)BB * CHW));
  }
}

extern "C" void kernel_launch(void* const* d_in, const int* in_sizes, int n_in,
                              void* d_out, int out_size, void* d_ws,
                              size_t ws_size, hipStream_t stream) {
  const float* sr = (const float*)d_in[0];
  const float* srema = (const float*)d_in[1];
  const float* hr = (const float*)d_in[2];
  float* out = (float*)d_out;

  float* p_sum = (float*)d_ws;
  float* p_sum2 = p_sum + NBLOCKS;
  float* p_loss = p_sum2 + NBLOCKS;

  wl1_main<<<NBLOCKS, 256, 0, stream>>>(sr, srema, hr, p_sum, p_sum2, p_loss);
  wl1_reduce<<<1, 1024, 0, stream>>>(p_sum, p_sum2, p_loss, out);
}